// Round 14
// baseline (219.166 us; speedup 1.0000x reference)
//
#include <hip/hip_runtime.h>
#include <math.h>

#define BB 32
#define CCH 224
#define TTT 2048
#define TPB 128            // t per tile in kf
#define NT  (TTT/TPB)      // 16 global tiles
#define CG  28             // chains (channels) per kf block (halo-optimal)
#define NCG (CCH/CG)       // 8
#define CPW 4              // channels per conv thread (7 conv waves)
#define NSLOT 8            // Is ring depth (tile lifetime 8 phases)
#define TROW 130           // f32 per transposed Is row (128 + 2 pad: 8B-align + bank-spread)

// LDS-only barrier: cross-wave deps in kf are all through LDS (IsT, bitsb).
// Stores stay fire-and-forget; prefetch loads stay in flight across barriers.
__device__ __forceinline__ void bar_lds() {
    asm volatile("s_waitcnt lgkmcnt(0)" ::: "memory");
    __builtin_amdgcn_s_barrier();
    asm volatile("" ::: "memory");
}

// ---------------------------------------------------------------------------
// kw v3: per (b,t): f64 dot over C -> w -> 7 symmetric Gaussian taps (f64).
// 1024-thread blocks: 256 t x 4 channel-quarters; grid (8,32).
// Summation order preserved exactly: p_q sequential, (p0+p1)+(p2+p3).
// ---------------------------------------------------------------------------
__global__ __launch_bounds__(1024) void kw(
    const float* __restrict__ x, const float* __restrict__ lw,
    double* __restrict__ kernG)
{
    __shared__ double sp[4][256];
    const int b  = blockIdx.y;
    const int tl = threadIdx.x & 255;          // t within block tile
    const int q  = threadIdx.x >> 8;           // channel quarter 0..3
    const int t  = blockIdx.x * 256 + tl;

    const float* xb  = x + (((size_t)(b * CCH + 56 * q)) << 11) + t;
    const float* lwq = lw + 56 * q;

    double p = 0.0;
    #pragma unroll 8
    for (int i = 0; i < 56; ++i)
        p += (double)xb[(size_t)i << 11] * (double)lwq[i];
    sp[q][tl] = p;
    __syncthreads();

    if (threadIdx.x < 256) {
        const int tt = blockIdx.x * 256 + threadIdx.x;
        double acc = (sp[0][threadIdx.x] + sp[1][threadIdx.x])
                   + (sp[2][threadIdx.x] + sp[3][threadIdx.x]);

        double w = 5.2 + acc * 9.6;
        w = fmin(fmax(w, 0.4), 10.0);
        double iw2 = 1.0 / (w * w);

        // norm over linspace(-60,60,130): symmetric -> 2x half-sum,
        // terms G^{(2u+1)^2} via power recurrence (2 exps total)
        const double s = 120.0 / 129.0;
        double G  = exp(-0.125 * s * s * iw2);
        double G2 = G * G, G4 = G2 * G2, G8 = G4 * G4;
        double term = G, cmul = G8, norm = G;
        for (int u = 1; u <= 64; ++u) { term *= cmul; cmul *= G8; norm += term; }
        norm *= 2.0;

        double P = exp(-0.5 * iw2), P2 = P * P;
        double a = 1.0, bm = P, inv = 1.0 / norm;
        double* kr = kernG + (size_t)(b * TTT + tt) * 7;
        kr[0] = inv;                      // center tap
        #pragma unroll
        for (int d = 1; d <= 6; ++d) {
            a *= bm; bm *= P2;
            kr[d] = a * inv;              // tap at distance d (symmetric)
        }
    }
}

// ---------------------------------------------------------------------------
// kf v14: fused conv + LIF scan + spikes; dual-segment scan in ONE wave.
// grid (8,32) x 512 threads. LDS = transposed f32 Is ring + bitsb (~118KB).
// wave0 lanes 0..27  = segment A: scans tiles 0..9 exactly (true init).
// wave0 lanes 32..59 = segment B: warms tiles 6..9 from mem=0 (W=512 steps,
//   residual 0.95^512*10 ~ 4e-11 — strictly safer than the validated W=640
//   [r10/r11 absmax 0] and below the r9-validated 2e-6 flip-free scale),
//   then outputs tiles 10..15.
// Fix vs v13 (which ran 110+ cyc/step): the scan's LDS reads. v6(f64/b64)=65
// cyc/step; r9+v13(f32 scalar b32)=~110 — strided b32 prefetch defeats the
// compiler's load batching. Here Is is TRANSPOSED [slot][ch][t] so scan lane
// c reads CONSECUTIVE t -> hand-written float2 (b64) loads, 8B-aligned
// (TROW=130), conv-write banks conflict-free (2 lanes/bank). Scan math and
// r5 step idiom untouched (f64, no carried bool).
// Schedule (phase k=1..10): A reads slot (k-1)&7; B reads (k+5)&7; conv
// writes (k+6)&7 [gaps 7,1 mod 8 -> no collision; tile t: written k=t-6,
// A-read k=t+1 < overwritten k=t+2]. issue tile k+8 (k<=7), conv k<=9.
// A out-write tile k-2 (k=2..11); B out tile k+4 (k=6..11). Phase 11 is
// store-only. Prologue: 2-deep PIPELINED issue/conv of tiles 0..6 (one
// exposed load latency, not seven) + issue 7,8.
// ---------------------------------------------------------------------------
__global__ __launch_bounds__(512) void kf(
    const float* __restrict__ x, const double* __restrict__ kernG,
    float* __restrict__ out)
{
    __shared__ float IsT[NSLOT][CG][TROW];             // 116,480 B
    __shared__ unsigned long long bitsb[2][2][CG][2];  // [parity][seg][c][half]

    const int b   = blockIdx.y;
    const int cgi = blockIdx.x;
    const int c0  = cgi * CG;
    const int tid = threadIdx.x;
    const int ctid = tid - 64;          // 0..447 for conv waves

    const float*  xbase = x + (((size_t)(b * CCH)) << 11);
    const double* kbase = kernG + (size_t)(b * TTT) * 7;
    float* obase = out + (((size_t)(b * CCH + c0)) << 11);

    double mem = 0.0;   // scan state; exact init for A, warm-start guess for B
    bool   r   = false;

    const int tl = ctid & 63;           // conv lane t within half
    const int cw = ctid >> 6;           // conv wave group 0..6
    const int cb = CPW * cw;            // first channel (relative) of group

    // issue all global loads for one tile into a reg set (conv waves only)
    auto issue = [&](int tile, float (&rv)[2][16], double (&kv)[2][7]) {
        const int gt0 = tile * TPB;
        #pragma unroll
        for (int h = 0; h < 2; ++h) {
            const int tt = gt0 + tl + 64 * h;
            #pragma unroll
            for (int i = 0; i < 16; ++i) {
                int cr = c0 + cb - 6 + i;
                rv[h][i] = (cr >= 0 && cr < CCH)
                         ? xbase[((size_t)cr << 11) + tt] : 0.f;
            }
            const double* kp = kbase + (size_t)tt * 7;
            #pragma unroll
            for (int i = 0; i < 7; ++i) kv[h][i] = kp[i];
        }
    };

    // conv one tile from a reg set into TRANSPOSED ring slot (f64 conv,
    // one f32 round). Store addr: slot + ch*TROW + t; banks (2ch+t)%32 ->
    // 2 lanes/bank across the wave (free).
    auto conv_store = [&](int slot, float (&rv)[2][16], double (&kv)[2][7]) {
        #pragma unroll
        for (int h = 0; h < 2; ++h) {
            double kk7[7];
            #pragma unroll
            for (int i = 0; i < 7; ++i) kk7[i] = kv[h][i];
            double xv[16];
            #pragma unroll
            for (int i = 0; i < 16; ++i) xv[i] = (double)rv[h][i];
            #pragma unroll
            for (int c = 0; c < CPW; ++c) {
                double acc = 0.0;
                #pragma unroll
                for (int kk = 0; kk < 13; ++kk) {
                    int d = kk < 6 ? 6 - kk : kk - 6;
                    acc = fma(xv[c + kk], kk7[d], acc);
                }
                double xvv = xv[c + 6];
                double dd  = xvv - acc;
                IsT[slot][cb + c][tl + 64 * h] =
                    (float)(xvv - (dd > 0.0 ? dd : 0.0));
            }
        }
    };

    // fire-and-forget spike store of one tile from a bitsb slot
    auto writeTile = [&](int t, int par, int seg) {
        const int t0o = t * TPB;
        const int c = ctid >> 4, q = ctid & 15;
        #pragma unroll
        for (int h = 0; h < 2; ++h) {
            unsigned long long bits = bitsb[par][seg][c][h] >> (4 * q);
            float4 v;
            v.x = (bits & 1ull) ? 1.0f : 0.0f;
            v.y = (bits & 2ull) ? 1.0f : 0.0f;
            v.z = (bits & 4ull) ? 1.0f : 0.0f;
            v.w = (bits & 8ull) ? 1.0f : 0.0f;
            *(float4*)(obase + ((size_t)c << 11) + t0o + 64 * h + 4 * q) = v;
        }
    };

    auto phase = [&](int k, float (&rv)[2][16], double (&kv)[2][7]) {
        if (tid >= 64) {
            if (k >= 2)  writeTile(k - 2, (k - 1) & 1, 0);   // A out (tiles 0..9)
            if (k >= 6)  writeTile(k + 4, (k - 1) & 1, 1);   // B out (tiles 10..15)
            if (k <= 9)  conv_store((k + 6) & 7, rv, kv);    // conv tile k+6
            if (k <= 7)  issue(k + 8, rv, kv);               // prefetch tile k+8
        } else if (k <= 10) {
            // dual-segment scan: lanes 0..27 = A (tile k-1), 32..59 = B (k+5)
            const int seg = tid >> 5;
            const int c   = tid & 31;
            const int myt = seg ? (k + 5) : (k - 1);
            __builtin_amdgcn_s_setprio(1);
            if (c < CG) {
                const float* isb = &IsT[myt & 7][c][0];   // 8B-aligned base
                unsigned long long bits0 = 0ull, bits1 = 0ull;
                double va[8], vb8[8], ca[8], cb2[8];
                #pragma unroll
                for (int j2 = 0; j2 < 4; ++j2) {
                    float2 p2 = *(const float2*)(isb + 2 * j2);
                    va[2 * j2]     = (double)p2.x;
                    va[2 * j2 + 1] = (double)p2.y;
                }
                #pragma unroll
                for (int j2 = 0; j2 < 8; ++j2) ca[j2] = va[j2] - 1.0;
                for (int g2 = 0; g2 < TPB; g2 += 16) {
                    #pragma unroll
                    for (int j2 = 0; j2 < 4; ++j2) {
                        float2 p2 = *(const float2*)(isb + g2 + 8 + 2 * j2);
                        vb8[2 * j2]     = (double)p2.x;
                        vb8[2 * j2 + 1] = (double)p2.y;
                    }
                    #pragma unroll
                    for (int j2 = 0; j2 < 8; ++j2) cb2[j2] = vb8[j2] - 1.0;
                    #pragma unroll
                    for (int j2 = 0; j2 < 8; ++j2) {
                        double m1 = fma(0.95, mem, va[j2]);
                        double m2 = fma(0.95, mem, ca[j2]);
                        mem = r ? m2 : m1;
                        r = mem > 1.0;
                        const int s = g2 + j2;
                        unsigned long long bbit =
                            (unsigned long long)(r ? 1 : 0) << (s & 63);
                        if (s < 64) bits0 |= bbit; else bits1 |= bbit;
                    }
                    if (g2 + 16 < TPB) {
                        #pragma unroll
                        for (int j2 = 0; j2 < 4; ++j2) {
                            float2 p2 = *(const float2*)(isb + g2 + 16 + 2 * j2);
                            va[2 * j2]     = (double)p2.x;
                            va[2 * j2 + 1] = (double)p2.y;
                        }
                        #pragma unroll
                        for (int j2 = 0; j2 < 8; ++j2) ca[j2] = va[j2] - 1.0;
                    }
                    #pragma unroll
                    for (int j2 = 0; j2 < 8; ++j2) {
                        double m1 = fma(0.95, mem, vb8[j2]);
                        double m2 = fma(0.95, mem, cb2[j2]);
                        mem = r ? m2 : m1;
                        r = mem > 1.0;
                        const int s = g2 + 8 + j2;
                        unsigned long long bbit =
                            (unsigned long long)(r ? 1 : 0) << (s & 63);
                        if (s < 64) bits0 |= bbit; else bits1 |= bbit;
                    }
                }
                bitsb[k & 1][seg][c][0] = bits0;
                bitsb[k & 1][seg][c][1] = bits1;
            }
            __builtin_amdgcn_s_setprio(0);
        }
        bar_lds();
    };

    // ping-pong register sets (statically indexed — rule #20)
    float  rA[2][16], rB[2][16];
    double kA[2][7],  kB[2][7];

    // ---- prologue: 2-deep pipelined conv of tiles 0..6; prefetch 7,8 ----
    // Only the first conv waits a full load latency; issue(i+2) lands under
    // conv(i)+conv(i+1). Parity: odd tiles in rB, even in rA (phase k odd
    // consumes rB).
    if (tid >= 64) {
        issue(0, rA, kA); issue(1, rB, kB);
        conv_store(0, rA, kA); issue(2, rA, kA);
        conv_store(1, rB, kB); issue(3, rB, kB);
        conv_store(2, rA, kA); issue(4, rA, kA);
        conv_store(3, rB, kB); issue(5, rB, kB);
        conv_store(4, rA, kA); issue(6, rA, kA);
        conv_store(5, rB, kB); issue(7, rB, kB);
        conv_store(6, rA, kA); issue(8, rA, kA);
    }
    bar_lds();

    // phases 1..11 (11 = store-only), unrolled by 2: odd phase = rB set
    for (int kk = 1; kk <= 11; kk += 2) {
        phase(kk, rB, kB);
        if (kk + 1 <= 11) phase(kk + 1, rA, kA);
    }
}

// ---------------------------------------------------------------------------
extern "C" void kernel_launch(void* const* d_in, const int* in_sizes, int n_in,
                              void* d_out, int out_size, void* d_ws, size_t ws_size,
                              hipStream_t stream)
{
    const float* x  = (const float*)d_in[0];   // (32,1,224,2048) f32
    const float* lw = (const float*)d_in[1];   // (1,224) f32
    float* out = (float*)d_out;                // (32,1,224,2048) f32

    double* kernG = (double*)d_ws;             // 65536 * 7 * 8 = 3,670,016 B

    kw<<<dim3(TTT / 256, BB), 1024, 0, stream>>>(x, lw, kernG);
    kf<<<dim3(NCG, BB), 512, 0, stream>>>(x, kernG, out);
}